// Round 17
// baseline (10907.405 us; speedup 1.0000x reference)
//
#include <hip/hip_runtime.h>

#define T_LEN 2048

typedef _Float16 f16x8 __attribute__((ext_vector_type(8)));
typedef float f32x4 __attribute__((ext_vector_type(4)));
typedef unsigned int u32;
typedef unsigned short u16;

// fast sigmoid: v_rcp_f32 (<=1 ulp) instead of IEEE fdiv (~11 instr at -O3)
__device__ __forceinline__ float frcp(float x) {
  float r;
  asm("v_rcp_f32 %0, %1" : "=v"(r) : "v"(x));
  return r;
}
__device__ __forceinline__ float fsigm(float v) { return frcp(1.f + __expf(-v)); }

// ---------- Phase 1: xg = x @ Wx + bias (+1 forget), f16, layout [d*4+p] ----
// (verified R14/R15)
__global__ __launch_bounds__(256) void xg_gemm(
    const float* __restrict__ x, const float* __restrict__ Wfw,
    const float* __restrict__ bfw, const float* __restrict__ Wbw,
    const float* __restrict__ bbw, u16* __restrict__ xg, int t0, int chunkT) {
  const int dir = blockIdx.z;
  const int mrow0 = blockIdx.x * 64;
  const int ncol0 = blockIdx.y * 64;
  const float* W = dir ? Wbw : Wfw;
  const float* bias = dir ? bbw : bfw;
  const int tid = threadIdx.x;
  const int w = tid >> 6, lane = tid & 63, l15 = lane & 15, l4 = lane >> 4;

  __shared__ _Float16 At[64 * 32];
  __shared__ _Float16 Bt[64 * 32];

  const int b = mrow0 / chunkT;
  const int sbase = mrow0 % chunkT;

  f32x4 acc0 = {0,0,0,0}, acc1 = {0,0,0,0}, acc2 = {0,0,0,0}, acc3 = {0,0,0,0};
  const int ar = tid >> 2, acq = tid & 3;
  const int bc = tid >> 2, bkq = tid & 3;

  for (int kk0 = 0; kk0 < 256; kk0 += 32) {
    {
      const int sloc = sbase + ar;
      const int tx = dir ? (T_LEN - 1 - (t0 + sloc)) : (t0 + sloc);
      const float* xr = x + ((size_t)b * T_LEN + tx) * 256 + kk0 + 8 * acq;
      f32x4 v0 = *(const f32x4*)xr;
      f32x4 v1 = *(const f32x4*)(xr + 4);
      union { _Float16 h[8]; uint4 q; } u;
#pragma unroll
      for (int j = 0; j < 4; ++j) { u.h[j] = (_Float16)v0[j]; u.h[4 + j] = (_Float16)v1[j]; }
      int byte = ar * 64 + 16 * acq;  byte ^= (ar & 3) << 4;
      *(uint4*)((char*)At + byte) = u.q;
    }
    {
      const float* wc = W + (size_t)(kk0 + 8 * bkq) * 1024 + ncol0 + bc;
      union { _Float16 h[8]; uint4 q; } u;
#pragma unroll
      for (int j = 0; j < 8; ++j) u.h[j] = (_Float16)wc[(size_t)j * 1024];
      int byte = bc * 64 + 16 * bkq;  byte ^= (bc & 3) << 4;
      *(uint4*)((char*)Bt + byte) = u.q;
    }
    __syncthreads();
    f16x8 bfrag;
    {
      const int col = w * 16 + l15;
      int byte = col * 64 + 16 * l4;  byte ^= (col & 3) << 4;
      bfrag = *(const f16x8*)((char*)Bt + byte);
    }
#define XG_MT(mt, accv)                                                   \
    { const int row = mt * 16 + l15;                                      \
      int byte = row * 64 + 16 * l4;  byte ^= (row & 3) << 4;             \
      f16x8 afrag = *(const f16x8*)((char*)At + byte);                    \
      accv = __builtin_amdgcn_mfma_f32_16x16x32_f16(afrag, bfrag, accv, 0, 0, 0); }
    XG_MT(0, acc0) XG_MT(1, acc1) XG_MT(2, acc2) XG_MT(3, acc3)
#undef XG_MT
    __syncthreads();
  }
  const int gcol = ncol0 + w * 16 + l15;
  const int pp = gcol >> 8, dd = gcol & 255;
  const float badd = bias[gcol] + ((pp == 2) ? 1.f : 0.f);
#define XG_ST(mt, accv)                                                   \
  _Pragma("unroll") for (int v = 0; v < 4; ++v) {                         \
    const int sloc = sbase + mt * 16 + 4 * l4 + v;                        \
    union { _Float16 hf; u16 us; } cv;                                    \
    cv.hf = (_Float16)(accv[v] + badd);                                   \
    xg[((size_t)(dir * 32 + b) * chunkT + sloc) * 1024 + dd * 4 + pp] = cv.us; }
  XG_ST(0, acc0) XG_ST(1, acc1) XG_ST(2, acc2) XG_ST(3, acc3)
#undef XG_ST
}

// ---------- Phase 2: recurrence, 4 WGs x 512 thr (8 waves), no exchange. ----
// Wave w: dims [32w..32w+32) x 4 parts. Wh K=256: kt0..5 = 48 named reg frags
// (192 regs; (512,2) allows up to 1024 unified/wave), kt6..7 in LDS (128KB).
// Cell fully in-register (R15-verified mapping), v_rcp sigmoid.
__global__ __launch_bounds__(512, 2) void rnn_chunk(
    const u16* __restrict__ xg, const float* __restrict__ Wfw,
    const float* __restrict__ Wbw, float* __restrict__ out,
    float* __restrict__ state_c, u16* __restrict__ state_h,
    int t0, int t1, int chunkT) {
  const int g = blockIdx.x;
  const int dir = g >> 1, bh = g & 1;
  const int tid = threadIdx.x;
  const int w = tid >> 6, lane = tid & 63, l15 = lane & 15, l4 = lane >> 4;
  const float* W = dir ? Wbw : Wfw;

  __shared__ u16 WL[2][4][8][2][512];   // 128KB: kt6..7 [kt2][p][w][half][lane*8]
  __shared__ _Float16 H[2][16 * 256];   // 16KB dbuf

  // ---- 48 NAMED weight fragments (kt0..5) ----
#define DECL_WB(kt) f16x8 wB##kt##00, wB##kt##01, wB##kt##10, wB##kt##11, \
                          wB##kt##20, wB##kt##21, wB##kt##30, wB##kt##31;
  DECL_WB(0) DECL_WB(1) DECL_WB(2) DECL_WB(3) DECL_WB(4) DECL_WB(5)
#undef DECL_WB
#define LOAD_WB1(kt, p, hf)                                               \
  { const int col = (p) * 256 + 32 * w + 16 * (hf) + l15;                 \
    f16x8 hh;                                                             \
    _Pragma("unroll") for (int j = 0; j < 8; ++j)                         \
      hh[j] = (_Float16)W[(size_t)(256 + (kt) * 32 + l4 * 8 + j) * 1024 + col]; \
    wB##kt##p##hf = hh; }
#define LOAD_WB(kt) LOAD_WB1(kt,0,0) LOAD_WB1(kt,0,1) LOAD_WB1(kt,1,0) LOAD_WB1(kt,1,1) \
                    LOAD_WB1(kt,2,0) LOAD_WB1(kt,2,1) LOAD_WB1(kt,3,0) LOAD_WB1(kt,3,1)
  LOAD_WB(0) LOAD_WB(1) LOAD_WB(2) LOAD_WB(3) LOAD_WB(4) LOAD_WB(5)
#undef LOAD_WB
#undef LOAD_WB1

  // ---- kt6..7 -> LDS (k rows 256+192..256+255) ----
#pragma unroll
  for (int kt2 = 0; kt2 < 2; ++kt2)
#pragma unroll
    for (int p = 0; p < 4; ++p)
#pragma unroll
      for (int hf = 0; hf < 2; ++hf) {
        const int col = p * 256 + 32 * w + 16 * hf + l15;
        union { _Float16 h[8]; uint4 q; } u;
#pragma unroll
        for (int j = 0; j < 8; ++j)
          u.h[j] = (_Float16)W[(size_t)(256 + 192 + kt2 * 32 + l4 * 8 + j) * 1024 + col];
        *(uint4*)&WL[kt2][p][w][hf][lane * 8] = u.q;
      }

  const int d0 = 32 * w + l15, d1 = d0 + 16;
  const int seq0 = 4 * l4;
#define HB(seqv, d) ((((seqv) * 512 + (d) * 2)) ^ (((seqv) & 7) << 4))
  const int hb0_0 = HB(seq0, d0), hb0_1 = HB(seq0 + 1, d0), hb0_2 = HB(seq0 + 2, d0), hb0_3 = HB(seq0 + 3, d0);
  const int hb1_0 = HB(seq0, d1), hb1_1 = HB(seq0 + 1, d1), hb1_2 = HB(seq0 + 2, d1), hb1_3 = HB(seq0 + 3, d1);
#undef HB
  // named AFRAG byte offsets (kt 0..7)
#define AFB(kt) ((l15 * 512 + (kt) * 64 + l4 * 16) ^ ((l15 & 7) << 4))
  const int af0 = AFB(0), af1 = AFB(1), af2 = AFB(2), af3 = AFB(3);
  const int af4 = AFB(4), af5 = AFB(5), af6 = AFB(6), af7 = AFB(7);
#undef AFB

  float c0_0, c0_1, c0_2, c0_3, c1_0, c1_1, c1_2, c1_3;
  {  // restore/init; stage h into H[0]
#define INITV(v)                                                           \
    { const int sidx = (dir * 32 + bh * 16 + seq0 + v) * 256 + d0;         \
      u16 hq0, hq1;                                                        \
      if (t0 == 0) { c0_##v = 0.f; c1_##v = 0.f; hq0 = 0; hq1 = 0; }       \
      else { c0_##v = state_c[sidx]; c1_##v = state_c[sidx + 16];          \
             hq0 = state_h[sidx]; hq1 = state_h[sidx + 16]; }              \
      *(u16*)((char*)H[0] + hb0_##v) = hq0;                                \
      *(u16*)((char*)H[0] + hb1_##v) = hq1; }
    INITV(0) INITV(1) INITV(2) INITV(3)
#undef INITV
  }
  __syncthreads();

  const int tx0 = dir ? (T_LEN - 1 - t0) : t0;
  const long outstep = dir ? -512 : 512;
  float* outp0 = out + ((size_t)(bh * 16 + seq0) * T_LEN + tx0) * 512 + dir * 256;
  float* outp1 = out + ((size_t)(bh * 16 + seq0 + 1) * T_LEN + tx0) * 512 + dir * 256;
  float* outp2 = out + ((size_t)(bh * 16 + seq0 + 2) * T_LEN + tx0) * 512 + dir * 256;
  float* outp3 = out + ((size_t)(bh * 16 + seq0 + 3) * T_LEN + tx0) * 512 + dir * 256;
  const u16* xgp0 = xg + (size_t)((dir * 32 + bh * 16 + seq0) * chunkT) * 1024 + d0 * 4;
  const u16* xgp1 = xg + (size_t)((dir * 32 + bh * 16 + seq0 + 1) * chunkT) * 1024 + d0 * 4;
  const u16* xgp2 = xg + (size_t)((dir * 32 + bh * 16 + seq0 + 2) * chunkT) * 1024 + d0 * 4;
  const u16* xgp3 = xg + (size_t)((dir * 32 + bh * 16 + seq0 + 3) * chunkT) * 1024 + d0 * 4;

#define AFRAG(kt) (*(const f16x8*)((const char*)Hc + af##kt))
#define MFMA8(kt, A)                                                      \
  a00 = __builtin_amdgcn_mfma_f32_16x16x32_f16(A, wB##kt##00, a00, 0, 0, 0); \
  a01 = __builtin_amdgcn_mfma_f32_16x16x32_f16(A, wB##kt##01, a01, 0, 0, 0); \
  a10 = __builtin_amdgcn_mfma_f32_16x16x32_f16(A, wB##kt##10, a10, 0, 0, 0); \
  a11 = __builtin_amdgcn_mfma_f32_16x16x32_f16(A, wB##kt##11, a11, 0, 0, 0); \
  a20 = __builtin_amdgcn_mfma_f32_16x16x32_f16(A, wB##kt##20, a20, 0, 0, 0); \
  a21 = __builtin_amdgcn_mfma_f32_16x16x32_f16(A, wB##kt##21, a21, 0, 0, 0); \
  a30 = __builtin_amdgcn_mfma_f32_16x16x32_f16(A, wB##kt##30, a30, 0, 0, 0); \
  a31 = __builtin_amdgcn_mfma_f32_16x16x32_f16(A, wB##kt##31, a31, 0, 0, 0);
#define MFMA8_LDS(kt2, A)                                                 \
  a00 = __builtin_amdgcn_mfma_f32_16x16x32_f16(A, *(const f16x8*)&WL[kt2][0][w][0][lane * 8], a00, 0, 0, 0); \
  a01 = __builtin_amdgcn_mfma_f32_16x16x32_f16(A, *(const f16x8*)&WL[kt2][0][w][1][lane * 8], a01, 0, 0, 0); \
  a10 = __builtin_amdgcn_mfma_f32_16x16x32_f16(A, *(const f16x8*)&WL[kt2][1][w][0][lane * 8], a10, 0, 0, 0); \
  a11 = __builtin_amdgcn_mfma_f32_16x16x32_f16(A, *(const f16x8*)&WL[kt2][1][w][1][lane * 8], a11, 0, 0, 0); \
  a20 = __builtin_amdgcn_mfma_f32_16x16x32_f16(A, *(const f16x8*)&WL[kt2][2][w][0][lane * 8], a20, 0, 0, 0); \
  a21 = __builtin_amdgcn_mfma_f32_16x16x32_f16(A, *(const f16x8*)&WL[kt2][2][w][1][lane * 8], a21, 0, 0, 0); \
  a30 = __builtin_amdgcn_mfma_f32_16x16x32_f16(A, *(const f16x8*)&WL[kt2][3][w][0][lane * 8], a30, 0, 0, 0); \
  a31 = __builtin_amdgcn_mfma_f32_16x16x32_f16(A, *(const f16x8*)&WL[kt2][3][w][1][lane * 8], a31, 0, 0, 0);

  for (int s = t0; s < t1; ++s) {
    const int cur = (s - t0) & 1;
    const _Float16* Hc = H[cur];
    char* Hn = (char*)H[cur ^ 1];

    ushort4 xa0 = *(const ushort4*)xgp0, xb0 = *(const ushort4*)(xgp0 + 64);
    ushort4 xa1 = *(const ushort4*)xgp1, xb1 = *(const ushort4*)(xgp1 + 64);
    ushort4 xa2 = *(const ushort4*)xgp2, xb2 = *(const ushort4*)(xgp2 + 64);
    ushort4 xa3 = *(const ushort4*)xgp3, xb3 = *(const ushort4*)(xgp3 + 64);

    f32x4 a00 = {0,0,0,0}, a01 = {0,0,0,0}, a10 = {0,0,0,0}, a11 = {0,0,0,0};
    f32x4 a20 = {0,0,0,0}, a21 = {0,0,0,0}, a30 = {0,0,0,0}, a31 = {0,0,0,0};

    { f16x8 A = AFRAG(0); MFMA8(0, A) }
    { f16x8 A = AFRAG(1); MFMA8(1, A) }
    { f16x8 A = AFRAG(2); MFMA8(2, A) }
    { f16x8 A = AFRAG(3); MFMA8(3, A) }
    { f16x8 A = AFRAG(4); MFMA8(4, A) }
    { f16x8 A = AFRAG(5); MFMA8(5, A) }
    { f16x8 A = AFRAG(6); MFMA8_LDS(0, A) }
    { f16x8 A = AFRAG(7); MFMA8_LDS(1, A) }

    // ---- cell (R15-verified mapping; v_rcp sigmoid) ----
#define CELL(v)                                                           \
    { float gi0 = a00[v] + (float)*(const _Float16*)&xa##v.x;             \
      float gj0 = a10[v] + (float)*(const _Float16*)&xa##v.y;             \
      float gf0 = a20[v] + (float)*(const _Float16*)&xa##v.z;             \
      float go0 = a30[v] + (float)*(const _Float16*)&xa##v.w;             \
      float gi1 = a01[v] + (float)*(const _Float16*)&xb##v.x;             \
      float gj1 = a11[v] + (float)*(const _Float16*)&xb##v.y;             \
      float gf1 = a21[v] + (float)*(const _Float16*)&xb##v.z;             \
      float go1 = a31[v] + (float)*(const _Float16*)&xb##v.w;             \
      c0_##v = c0_##v * fsigm(gf0) + fsigm(gi0) * (2.f * fsigm(gj0 + gj0) - 1.f); \
      c1_##v = c1_##v * fsigm(gf1) + fsigm(gi1) * (2.f * fsigm(gj1 + gj1) - 1.f); \
      float h0 = (2.f * fsigm(c0_##v + c0_##v) - 1.f) * fsigm(go0);       \
      float h1 = (2.f * fsigm(c1_##v + c1_##v) - 1.f) * fsigm(go1);       \
      union { _Float16 hf; u16 us; } q0, q1;                              \
      q0.hf = (_Float16)h0; q1.hf = (_Float16)h1;                         \
      *(u16*)(Hn + hb0_##v) = q0.us;                                      \
      *(u16*)(Hn + hb1_##v) = q1.us;                                      \
      __builtin_nontemporal_store(h0, outp##v + d0);                      \
      __builtin_nontemporal_store(h1, outp##v + d1); }
    CELL(0) CELL(1) CELL(2) CELL(3)
#undef CELL

    xgp0 += 1024; xgp1 += 1024; xgp2 += 1024; xgp3 += 1024;
    outp0 += outstep; outp1 += outstep; outp2 += outstep; outp3 += outstep;
    __syncthreads();
  }
#undef AFRAG
#undef MFMA8
#undef MFMA8_LDS

  // save state
  {
    char* Hl = (char*)H[(t1 - t0) & 1];
#define SAVEV(v)                                                          \
    { const int sidx = (dir * 32 + bh * 16 + seq0 + v) * 256 + d0;        \
      state_c[sidx] = c0_##v; state_c[sidx + 16] = c1_##v;                \
      state_h[sidx] = *(const u16*)(Hl + hb0_##v);                        \
      state_h[sidx + 16] = *(const u16*)(Hl + hb1_##v); }
    SAVEV(0) SAVEV(1) SAVEV(2) SAVEV(3)
#undef SAVEV
  }
}

extern "C" void kernel_launch(void* const* d_in, const int* in_sizes, int n_in,
                              void* d_out, int out_size, void* d_ws,
                              size_t ws_size, hipStream_t stream) {
  const float* x = (const float*)d_in[0];
  const float* Wfw = (const float*)d_in[1];
  const float* bfw = (const float*)d_in[2];
  const float* Wbw = (const float*)d_in[3];
  const float* bbw = (const float*)d_in[4];
  float* out = (float*)d_out;

  // ws: [0,64K) state_c | [64K,96K) state_h | [1M,..) xg
  float* state_c = (float*)d_ws;
  u16* state_h = (u16*)((char*)d_ws + 64 * 1024);
  u16* xg = (u16*)((char*)d_ws + (1 << 20));

  int chunkT = 1024;
  while (chunkT > 64 && (size_t)131072 * chunkT + (1 << 20) > ws_size)
    chunkT >>= 1;

  for (int t0 = 0; t0 < T_LEN; t0 += chunkT) {
    xg_gemm<<<dim3((32 * chunkT) / 64, 16, 2), dim3(256), 0, stream>>>(
        x, Wfw, bfw, Wbw, bbw, xg, t0, chunkT);
    rnn_chunk<<<dim3(4), dim3(512), 0, stream>>>(
        xg, Wfw, Wbw, out, state_c, state_h, t0, t0 + chunkT, chunkT);
  }
}